// Round 1
// baseline (322.091 us; speedup 1.0000x reference)
//
#include <hip/hip_runtime.h>

// SparseNodeConv: out = segment_sum((X@W)[edge_dst] by edge_src) + X@R + bias
// Strategy: AX = segment_sum(X[dst] by src)  (aggregate RAW features, linearity)
//           out = [AX | X](bf16) @ [W; R](bf16) + bias   via MFMA 16x16x32 bf16
//
// N = 50000, E = 1600000, D = 128 (derived from in_sizes at launch).

typedef __attribute__((ext_vector_type(8))) short bf16x8;
typedef __attribute__((ext_vector_type(4))) float f32x4;

__device__ __forceinline__ unsigned f2bf(float f) {
  unsigned u = __float_as_uint(f);
  return (u + 0x7fffu + ((u >> 16) & 1u)) >> 16;  // RNE
}
__device__ __forceinline__ unsigned pack2(float lo, float hi) {
  return f2bf(lo) | (f2bf(hi) << 16);
}
__device__ __forceinline__ float bflo(unsigned v) { return __uint_as_float(v << 16); }
__device__ __forceinline__ float bfhi(unsigned v) { return __uint_as_float(v & 0xffff0000u); }

// ---------- X (f32) -> Xb (bf16 packed u32 pairs) ----------
__global__ __launch_bounds__(256) void k_convert(const float4* __restrict__ X,
                                                 uint2* __restrict__ Xb, int n4) {
  int stride = gridDim.x * blockDim.x;
  for (int i = blockIdx.x * blockDim.x + threadIdx.x; i < n4; i += stride) {
    float4 v = X[i];
    uint2 o;
    o.x = pack2(v.x, v.y);
    o.y = pack2(v.z, v.w);
    Xb[i] = o;
  }
}

// ---------- histogram of edge_src ----------
__global__ __launch_bounds__(256) void k_hist(const int* __restrict__ src,
                                              int* __restrict__ cnt, int E_) {
  int stride = gridDim.x * blockDim.x;
  for (int i = blockIdx.x * blockDim.x + threadIdx.x; i < E_; i += stride)
    atomicAdd(&cnt[src[i]], 1);
}

// ---------- 3-kernel exclusive scan over counts (N=50000, nb=196<=256) ----------
__device__ __forceinline__ int incl_scan256(int v, int tid) {
  int lane = tid & 63, w = tid >> 6;
  int x = v;
#pragma unroll
  for (int d = 1; d < 64; d <<= 1) {
    int o = __shfl_up(x, d, 64);
    if (lane >= d) x += o;
  }
  __shared__ int wsum[4];
  if (lane == 63) wsum[w] = x;
  __syncthreads();
  if (w > 0) x += wsum[0];
  if (w > 1) x += wsum[1];
  if (w > 2) x += wsum[2];
  return x;
}

__global__ __launch_bounds__(256) void k_scan1(const int* __restrict__ cnt,
                                               int* __restrict__ excl,
                                               int* __restrict__ blksum, int N_) {
  int gid = blockIdx.x * 256 + threadIdx.x;
  int v = (gid < N_) ? cnt[gid] : 0;
  int incl = incl_scan256(v, threadIdx.x);
  if (gid < N_) excl[gid] = incl - v;
  if (threadIdx.x == 255) blksum[blockIdx.x] = incl;
}

__global__ __launch_bounds__(256) void k_scan2(int* __restrict__ blksum, int nb) {
  int t = threadIdx.x;
  int v = (t < nb) ? blksum[t] : 0;
  int incl = incl_scan256(v, t);
  if (t < nb) blksum[t] = incl - v;  // exclusive, in place (reads precede sync)
}

__global__ __launch_bounds__(256) void k_scan3(int* __restrict__ excl,
                                               const int* __restrict__ blkoff,
                                               int* __restrict__ cursor, int N_, int E_) {
  int gid = blockIdx.x * 256 + threadIdx.x;
  if (gid < N_) {
    int o = excl[gid] + blkoff[blockIdx.x];
    excl[gid] = o;
    cursor[gid] = o;
  }
  if (gid == 0) excl[N_] = E_;
}

// ---------- bucket scatter: sdst[bucket pos] = dst ----------
__global__ __launch_bounds__(256) void k_scatter(const int* __restrict__ src,
                                                 const int* __restrict__ dst,
                                                 int* __restrict__ cursor,
                                                 int* __restrict__ sdst, int E_) {
  int stride = gridDim.x * blockDim.x;
  for (int i = blockIdx.x * blockDim.x + threadIdx.x; i < E_; i += stride) {
    int s = src[i];
    int p = atomicAdd(&cursor[s], 1);
    sdst[p] = dst[i];
  }
}

// ---------- aggregation: AXb[i] = sum over bucket i of Xb[dst] ----------
// one wave per node; lane owns one u32 (2 bf16 cols); fp32 accumulate
__global__ __launch_bounds__(256) void k_agg(const unsigned* __restrict__ Xb,
                                             const int* __restrict__ offs,
                                             const int* __restrict__ sdst,
                                             unsigned* __restrict__ AXb, int N_) {
  int wid = (blockIdx.x * 256 + threadIdx.x) >> 6;
  int lane = threadIdx.x & 63;
  if (wid >= N_) return;
  int j = offs[wid], end = offs[wid + 1];
  float a0 = 0.f, a1 = 0.f;
  for (; j + 4 <= end; j += 4) {
    int d0 = sdst[j], d1 = sdst[j + 1], d2 = sdst[j + 2], d3 = sdst[j + 3];
    unsigned v0 = Xb[(size_t)d0 * 64 + lane];
    unsigned v1 = Xb[(size_t)d1 * 64 + lane];
    unsigned v2 = Xb[(size_t)d2 * 64 + lane];
    unsigned v3 = Xb[(size_t)d3 * 64 + lane];
    a0 += bflo(v0); a1 += bfhi(v0);
    a0 += bflo(v1); a1 += bfhi(v1);
    a0 += bflo(v2); a1 += bfhi(v2);
    a0 += bflo(v3); a1 += bfhi(v3);
  }
  for (; j < end; ++j) {
    unsigned v = Xb[(size_t)sdst[j] * 64 + lane];
    a0 += bflo(v); a1 += bfhi(v);
  }
  AXb[(size_t)wid * 64 + lane] = pack2(a0, a1);
}

// ---------- GEMM: out[N,128] = AXb@W + Xb@R + bias (MFMA 16x16x32 bf16) ----------
// Block = 4 waves; wave computes 16 rows x 128 cols. B kept transposed in LDS:
// Bt[col][k], row stride 136 shorts (272 B = 17*16: 16B-aligned b128 reads,
// bank start = 4*(col+g) mod 32 -> 2-way conflict only (free).
__global__ __launch_bounds__(256) void k_gemm(const unsigned* __restrict__ AXb,
                                              const unsigned* __restrict__ Xb,
                                              const float* __restrict__ Wg,
                                              const float* __restrict__ Rg,
                                              const float* __restrict__ bias,
                                              float* __restrict__ out, int N_) {
  __shared__ __align__(16) unsigned short Bt[128][136];
  int tid = threadIdx.x;
  int wave = tid >> 6, lane = tid & 63;
  int r = lane & 15, g = lane >> 4;
  int rowBase = (blockIdx.x * 4 + wave) * 16;
  int arow = rowBase + r;
  if (arow >= N_) arow = 0;  // clamp; stores are guarded

  // A fragments (lane: row = l&15, k = (l>>4)*8 + i within each K=32 step)
  bf16x8 fa[4], fx[4];
  const bf16x8* pA = (const bf16x8*)(AXb + (size_t)arow * 64);
  const bf16x8* pX = (const bf16x8*)(Xb + (size_t)arow * 64);
#pragma unroll
  for (int kk = 0; kk < 4; ++kk) {
    fa[kk] = pA[kk * 4 + g];
    fx[kk] = pX[kk * 4 + g];
  }

  f32x4 acc[8];
#pragma unroll
  for (int n = 0; n < 8; ++n) acc[n] = (f32x4){0.f, 0.f, 0.f, 0.f};

  // pass 1: stage W^T into LDS, multiply AX @ W
  for (int e = tid; e < 128 * 32; e += 256) {  // 4096 float4s of W
    int c4 = (e & 31) * 4;
    int k = e >> 5;
    float4 v = *(const float4*)&Wg[k * 128 + c4];
    Bt[c4 + 0][k] = (unsigned short)f2bf(v.x);
    Bt[c4 + 1][k] = (unsigned short)f2bf(v.y);
    Bt[c4 + 2][k] = (unsigned short)f2bf(v.z);
    Bt[c4 + 3][k] = (unsigned short)f2bf(v.w);
  }
  __syncthreads();
#pragma unroll
  for (int n = 0; n < 8; ++n) {
    int col = n * 16 + r;
#pragma unroll
    for (int kk = 0; kk < 4; ++kk) {
      bf16x8 fb = *(const bf16x8*)&Bt[col][kk * 32 + g * 8];
      acc[n] = __builtin_amdgcn_mfma_f32_16x16x32_bf16(fa[kk], fb, acc[n], 0, 0, 0);
    }
  }
  __syncthreads();

  // pass 2: stage R^T into LDS, multiply X @ R
  for (int e = tid; e < 128 * 32; e += 256) {
    int c4 = (e & 31) * 4;
    int k = e >> 5;
    float4 v = *(const float4*)&Rg[k * 128 + c4];
    Bt[c4 + 0][k] = (unsigned short)f2bf(v.x);
    Bt[c4 + 1][k] = (unsigned short)f2bf(v.y);
    Bt[c4 + 2][k] = (unsigned short)f2bf(v.z);
    Bt[c4 + 3][k] = (unsigned short)f2bf(v.w);
  }
  __syncthreads();
#pragma unroll
  for (int n = 0; n < 8; ++n) {
    int col = n * 16 + r;
#pragma unroll
    for (int kk = 0; kk < 4; ++kk) {
      bf16x8 fb = *(const bf16x8*)&Bt[col][kk * 32 + g * 8];
      acc[n] = __builtin_amdgcn_mfma_f32_16x16x32_bf16(fx[kk], fb, acc[n], 0, 0, 0);
    }
  }

  // epilogue: D mapping col = l&15, row = (l>>4)*4 + reg
#pragma unroll
  for (int n = 0; n < 8; ++n) {
    int col = n * 16 + r;
    float bv = bias[col];
#pragma unroll
    for (int jj = 0; jj < 4; ++jj) {
      int row = rowBase + g * 4 + jj;
      if (row < N_) out[(size_t)row * 128 + col] = acc[n][jj] + bv;
    }
  }
}

extern "C" void kernel_launch(void* const* d_in, const int* in_sizes, int n_in,
                              void* d_out, int out_size, void* d_ws, size_t ws_size,
                              hipStream_t stream) {
  const float* X = (const float*)d_in[0];
  const int* esrc = (const int*)d_in[1];
  const int* edst = (const int*)d_in[2];
  const float* Wg = (const float*)d_in[3];
  const float* Rg = (const float*)d_in[4];
  const float* bias = (const float*)d_in[5];
  float* out = (float*)d_out;

  int ND = in_sizes[0];  // N*D
  int E = in_sizes[1];
  int N = ND / 128;

  // workspace layout (~32.6 MB total)
  char* ws = (char*)d_ws;
  size_t off = 0;
  auto wsalloc = [&](size_t b) {
    char* p = ws + off;
    off = (off + b + 255) & ~(size_t)255;
    return p;
  };
  int* cnt = (int*)wsalloc((size_t)N * 4);
  int* offs = (int*)wsalloc((size_t)(N + 1) * 4);
  int* blk = (int*)wsalloc(1024 * 4);
  int* cursor = (int*)wsalloc((size_t)N * 4);
  int* sdst = (int*)wsalloc((size_t)E * 4);
  unsigned* Xb = (unsigned*)wsalloc((size_t)N * 64 * 4);
  unsigned* AXb = (unsigned*)wsalloc((size_t)N * 64 * 4);

  hipMemsetAsync(cnt, 0, (size_t)N * 4, stream);
  k_convert<<<2048, 256, 0, stream>>>((const float4*)X, (uint2*)Xb, ND / 4);
  k_hist<<<2048, 256, 0, stream>>>(esrc, cnt, E);
  int nb = (N + 255) / 256;  // 196 (must be <= 256)
  k_scan1<<<nb, 256, 0, stream>>>(cnt, offs, blk, N);
  k_scan2<<<1, 256, 0, stream>>>(blk, nb);
  k_scan3<<<nb, 256, 0, stream>>>(offs, blk, cursor, N, E);
  k_scatter<<<2048, 256, 0, stream>>>(esrc, edst, cursor, sdst, E);
  k_agg<<<(N + 3) / 4, 256, 0, stream>>>(Xb, offs, sdst, AXb, N);
  k_gemm<<<(N + 63) / 64, 256, 0, stream>>>(AXb, Xb, Wg, Rg, bias, out, N);
}

// Round 4
// 227.303 us; speedup vs baseline: 1.4170x; 1.4170x over previous
//
#include <hip/hip_runtime.h>

// SparseNodeConv: out = segment_sum((X@W)[edge_dst] by edge_src) + X@R + bias
// Strategy: AX = segment_sum(X[dst] by src)  (aggregate RAW features, linearity)
//           out = [AX | X](bf16) @ [W; R](bf16) + bias   via MFMA 16x16x32 bf16
//
// Edge grouping by src via two-level counting sort:
//  pass A (k_bucket): per-4096-edge-block LDS counting sort into 256-node
//    coarse buckets -> contiguous ~84B runs into packs[] (out-of-place).
//  pass B (k_fine): one block per bucket streams packs, writes dst to exact
//    CSR slot sdst[offs[src]+rank]; writes confined to bucket's 32KB window
//    (L2-local). Only ~2KB LDS -- no capacity assumptions.
// N = 50000, E = 1600000, D = 128. Assumes N < 65536 (dst fits 16 bits).

typedef __attribute__((ext_vector_type(8))) short bf16x8;
typedef __attribute__((ext_vector_type(4))) float f32x4;

#define BSH 8  // coarse bucket = 256 nodes

__device__ __forceinline__ unsigned f2bf(float f) {
  unsigned u = __float_as_uint(f);
  return (u + 0x7fffu + ((u >> 16) & 1u)) >> 16;  // RNE
}
__device__ __forceinline__ unsigned pack2(float lo, float hi) {
  return f2bf(lo) | (f2bf(hi) << 16);
}
__device__ __forceinline__ float bflo(unsigned v) { return __uint_as_float(v << 16); }
__device__ __forceinline__ float bfhi(unsigned v) { return __uint_as_float(v & 0xffff0000u); }

// ---------- X (f32) -> Xb (bf16 packed u32 pairs) ----------
__global__ __launch_bounds__(256) void k_convert(const float4* __restrict__ X,
                                                 uint2* __restrict__ Xb, int n4) {
  int stride = gridDim.x * blockDim.x;
  for (int i = blockIdx.x * blockDim.x + threadIdx.x; i < n4; i += stride) {
    float4 v = X[i];
    uint2 o;
    o.x = pack2(v.x, v.y);
    o.y = pack2(v.z, v.w);
    Xb[i] = o;
  }
}

// ---------- histogram of edge_src ----------
__global__ __launch_bounds__(256) void k_hist(const int* __restrict__ src,
                                              int* __restrict__ cnt, int E_) {
  int stride = gridDim.x * blockDim.x;
  for (int i = blockIdx.x * blockDim.x + threadIdx.x; i < E_; i += stride)
    atomicAdd(&cnt[src[i]], 1);
}

// ---------- 3-kernel exclusive scan over counts (N=50000, nb=196<=256) ----------
__device__ __forceinline__ int incl_scan256(int v, int tid) {
  int lane = tid & 63, w = tid >> 6;
  int x = v;
#pragma unroll
  for (int d = 1; d < 64; d <<= 1) {
    int o = __shfl_up(x, d, 64);
    if (lane >= d) x += o;
  }
  __shared__ int wsum[4];
  if (lane == 63) wsum[w] = x;
  __syncthreads();
  if (w > 0) x += wsum[0];
  if (w > 1) x += wsum[1];
  if (w > 2) x += wsum[2];
  return x;
}

__global__ __launch_bounds__(256) void k_scan1(const int* __restrict__ cnt,
                                               int* __restrict__ excl,
                                               int* __restrict__ blksum, int N_) {
  int gid = blockIdx.x * 256 + threadIdx.x;
  int v = (gid < N_) ? cnt[gid] : 0;
  int incl = incl_scan256(v, threadIdx.x);
  if (gid < N_) excl[gid] = incl - v;
  if (threadIdx.x == 255) blksum[blockIdx.x] = incl;
}

__global__ __launch_bounds__(256) void k_scan2(int* __restrict__ blksum, int nb) {
  int t = threadIdx.x;
  int v = (t < nb) ? blksum[t] : 0;
  int incl = incl_scan256(v, t);
  if (t < nb) blksum[t] = incl - v;  // exclusive, in place (reads precede sync)
}

__global__ __launch_bounds__(256) void k_scan3(int* __restrict__ excl,
                                               const int* __restrict__ blkoff,
                                               int* __restrict__ cursorC, int N_, int E_) {
  int gid = blockIdx.x * 256 + threadIdx.x;
  if (gid < N_) {
    int o = excl[gid] + blkoff[blockIdx.x];
    excl[gid] = o;
    if ((gid & 255) == 0) cursorC[gid >> BSH] = o;  // coarse bucket cursor seed
  }
  if (gid == 0) excl[N_] = E_;
}

// ---------- pass A: coarse scatter into 256-node buckets ----------
// chunk = 4096 edges / block; per-block LDS counting sort; one global atomic
// reservation per (block,bucket) so writes are ~84B contiguous runs.
// pack = (src&255)<<16 | dst   (dst < 65536)
__global__ __launch_bounds__(256) void k_bucket(const int* __restrict__ src,
                                                const int* __restrict__ dst,
                                                int* __restrict__ cursorC,
                                                unsigned* __restrict__ packs,
                                                int E_, int K_) {
  __shared__ int lcnt[256];
  __shared__ int lbase[256];
  __shared__ unsigned lsrc[4096];
  __shared__ unsigned ldst[4096];
  int base = blockIdx.x * 4096;
  int n = min(4096, E_ - base);
  if (threadIdx.x < K_) lcnt[threadIdx.x] = 0;
  __syncthreads();
  for (int i = threadIdx.x; i < n; i += 256) {
    unsigned s = (unsigned)src[base + i];
    unsigned d = (unsigned)dst[base + i];
    lsrc[i] = s;
    ldst[i] = d;
    atomicAdd(&lcnt[s >> BSH], 1);
  }
  __syncthreads();
  if (threadIdx.x < K_) {
    int c = lcnt[threadIdx.x];
    lbase[threadIdx.x] = (c > 0) ? atomicAdd(&cursorC[threadIdx.x], c) : 0;
    lcnt[threadIdx.x] = 0;  // reuse as local cursor
  }
  __syncthreads();
  for (int i = threadIdx.x; i < n; i += 256) {
    unsigned s = lsrc[i], d = ldst[i];
    int b = s >> BSH;
    int r = atomicAdd(&lcnt[b], 1);
    packs[lbase[b] + r] = ((s & 255u) << 16) | d;
  }
}

// ---------- pass B: fine scatter to CSR order (out-of-place, ~2KB LDS) ----------
// One block per bucket; stream the bucket's packs (coalesced), write dst to
// sdst[offs[src]+rank]. All writes within the bucket's 32KB range -> L2-local.
__global__ __launch_bounds__(256) void k_fine(const int* __restrict__ offs,
                                              const unsigned* __restrict__ packs,
                                              unsigned* __restrict__ sdst, int N_) {
  __shared__ int lcur[256];
  __shared__ int loffs[257];
  int b = blockIdx.x;
  int nodeBase = b << BSH;
  int nNodes = min(256, N_ - nodeBase);
  // NOTE: need nNodes+1 entries (up to 257) -- strided loop, NOT a single
  // predicated store (256 threads cannot cover 257 slots; that bug caused
  // an uninitialized loffs[256] -> huge n -> OOB writes -> device abort).
  for (int t = threadIdx.x; t <= nNodes; t += 256) loffs[t] = offs[nodeBase + t];
  if (threadIdx.x < 256) lcur[threadIdx.x] = 0;
  __syncthreads();
  int beg = loffs[0];
  int n = loffs[nNodes] - beg;  // bucket edge count
  for (int i = threadIdx.x; i < n; i += 256) {
    unsigned p = packs[beg + i];
    int sl = p >> 16;
    unsigned d = p & 0xffffu;
    int r = atomicAdd(&lcur[sl], 1);
    sdst[loffs[sl] + r] = d;
  }
}

// ---------- aggregation: AXb[i] = sum over bucket i of Xb[dst] ----------
// one wave per node; lane owns one u32 (2 bf16 cols); fp32 accumulate
__global__ __launch_bounds__(256) void k_agg(const unsigned* __restrict__ Xb,
                                             const int* __restrict__ offs,
                                             const int* __restrict__ sdst,
                                             unsigned* __restrict__ AXb, int N_) {
  int wid = (blockIdx.x * 256 + threadIdx.x) >> 6;
  int lane = threadIdx.x & 63;
  if (wid >= N_) return;
  int j = offs[wid], end = offs[wid + 1];
  float a0 = 0.f, a1 = 0.f;
  for (; j + 4 <= end; j += 4) {
    int d0 = sdst[j], d1 = sdst[j + 1], d2 = sdst[j + 2], d3 = sdst[j + 3];
    unsigned v0 = Xb[(size_t)d0 * 64 + lane];
    unsigned v1 = Xb[(size_t)d1 * 64 + lane];
    unsigned v2 = Xb[(size_t)d2 * 64 + lane];
    unsigned v3 = Xb[(size_t)d3 * 64 + lane];
    a0 += bflo(v0); a1 += bfhi(v0);
    a0 += bflo(v1); a1 += bfhi(v1);
    a0 += bflo(v2); a1 += bfhi(v2);
    a0 += bflo(v3); a1 += bfhi(v3);
  }
  for (; j < end; ++j) {
    unsigned v = Xb[(size_t)sdst[j] * 64 + lane];
    a0 += bflo(v); a1 += bfhi(v);
  }
  AXb[(size_t)wid * 64 + lane] = pack2(a0, a1);
}

// ---------- GEMM: out[N,128] = AXb@W + Xb@R + bias (MFMA 16x16x32 bf16) ----------
__global__ __launch_bounds__(256) void k_gemm(const unsigned* __restrict__ AXb,
                                              const unsigned* __restrict__ Xb,
                                              const float* __restrict__ Wg,
                                              const float* __restrict__ Rg,
                                              const float* __restrict__ bias,
                                              float* __restrict__ out, int N_) {
  __shared__ __align__(16) unsigned short Bt[128][136];
  int tid = threadIdx.x;
  int wave = tid >> 6, lane = tid & 63;
  int r = lane & 15, g = lane >> 4;
  int rowBase = (blockIdx.x * 4 + wave) * 16;
  int arow = rowBase + r;
  if (arow >= N_) arow = 0;  // clamp; stores are guarded

  bf16x8 fa[4], fx[4];
  const bf16x8* pA = (const bf16x8*)(AXb + (size_t)arow * 64);
  const bf16x8* pX = (const bf16x8*)(Xb + (size_t)arow * 64);
#pragma unroll
  for (int kk = 0; kk < 4; ++kk) {
    fa[kk] = pA[kk * 4 + g];
    fx[kk] = pX[kk * 4 + g];
  }

  f32x4 acc[8];
#pragma unroll
  for (int n = 0; n < 8; ++n) acc[n] = (f32x4){0.f, 0.f, 0.f, 0.f};

  for (int e = tid; e < 128 * 32; e += 256) {
    int c4 = (e & 31) * 4;
    int k = e >> 5;
    float4 v = *(const float4*)&Wg[k * 128 + c4];
    Bt[c4 + 0][k] = (unsigned short)f2bf(v.x);
    Bt[c4 + 1][k] = (unsigned short)f2bf(v.y);
    Bt[c4 + 2][k] = (unsigned short)f2bf(v.z);
    Bt[c4 + 3][k] = (unsigned short)f2bf(v.w);
  }
  __syncthreads();
#pragma unroll
  for (int n = 0; n < 8; ++n) {
    int col = n * 16 + r;
#pragma unroll
    for (int kk = 0; kk < 4; ++kk) {
      bf16x8 fb = *(const bf16x8*)&Bt[col][kk * 32 + g * 8];
      acc[n] = __builtin_amdgcn_mfma_f32_16x16x32_bf16(fa[kk], fb, acc[n], 0, 0, 0);
    }
  }
  __syncthreads();

  for (int e = tid; e < 128 * 32; e += 256) {
    int c4 = (e & 31) * 4;
    int k = e >> 5;
    float4 v = *(const float4*)&Rg[k * 128 + c4];
    Bt[c4 + 0][k] = (unsigned short)f2bf(v.x);
    Bt[c4 + 1][k] = (unsigned short)f2bf(v.y);
    Bt[c4 + 2][k] = (unsigned short)f2bf(v.z);
    Bt[c4 + 3][k] = (unsigned short)f2bf(v.w);
  }
  __syncthreads();
#pragma unroll
  for (int n = 0; n < 8; ++n) {
    int col = n * 16 + r;
#pragma unroll
    for (int kk = 0; kk < 4; ++kk) {
      bf16x8 fb = *(const bf16x8*)&Bt[col][kk * 32 + g * 8];
      acc[n] = __builtin_amdgcn_mfma_f32_16x16x32_bf16(fx[kk], fb, acc[n], 0, 0, 0);
    }
  }

#pragma unroll
  for (int n = 0; n < 8; ++n) {
    int col = n * 16 + r;
    float bv = bias[col];
#pragma unroll
    for (int jj = 0; jj < 4; ++jj) {
      int row = rowBase + g * 4 + jj;
      if (row < N_) out[(size_t)row * 128 + col] = acc[n][jj] + bv;
    }
  }
}

extern "C" void kernel_launch(void* const* d_in, const int* in_sizes, int n_in,
                              void* d_out, int out_size, void* d_ws, size_t ws_size,
                              hipStream_t stream) {
  const float* X = (const float*)d_in[0];
  const int* esrc = (const int*)d_in[1];
  const int* edst = (const int*)d_in[2];
  const float* Wg = (const float*)d_in[3];
  const float* Rg = (const float*)d_in[4];
  const float* bias = (const float*)d_in[5];
  float* out = (float*)d_out;

  int ND = in_sizes[0];  // N*D
  int E = in_sizes[1];
  int N = ND / 128;
  int K = (N + 255) >> BSH;  // 196 coarse buckets

  // persistent workspace (~32.2 MB)
  char* ws = (char*)d_ws;
  size_t off = 0;
  auto wsalloc = [&](size_t b) {
    char* p = ws + off;
    off = (off + b + 255) & ~(size_t)255;
    return p;
  };
  int* offs = (int*)wsalloc((size_t)(N + 1) * 4);
  unsigned* sdst = (unsigned*)wsalloc((size_t)E * 4);
  unsigned* Xb = (unsigned*)wsalloc((size_t)N * 64 * 4);
  unsigned* AXb = (unsigned*)wsalloc((size_t)N * 64 * 4);
  // transient aliases inside the AXb region (all dead before k_agg writes AXb):
  unsigned* packs = AXb;                       // E u32 (6.4MB <= 12.8MB)
  int* cnt = (int*)(AXb + (size_t)E);          // N ints
  int* blk = cnt + ((size_t)N + 64);           // 1024 ints
  int* cursorC = blk + 1024;                   // K ints

  hipMemsetAsync(cnt, 0, (size_t)N * 4, stream);
  k_convert<<<2048, 256, 0, stream>>>((const float4*)X, (uint2*)Xb, ND / 4);
  k_hist<<<2048, 256, 0, stream>>>(esrc, cnt, E);
  int nb = (N + 255) / 256;
  k_scan1<<<nb, 256, 0, stream>>>(cnt, offs, blk, N);
  k_scan2<<<1, 256, 0, stream>>>(blk, nb);
  k_scan3<<<nb, 256, 0, stream>>>(offs, blk, cursorC, N, E);
  k_bucket<<<(E + 4095) / 4096, 256, 0, stream>>>(esrc, edst, cursorC, packs, E, K);
  k_fine<<<K, 256, 0, stream>>>(offs, packs, sdst, N);
  k_agg<<<(N + 3) / 4, 256, 0, stream>>>(Xb, offs, (const int*)sdst, AXb, N);
  k_gemm<<<(N + 63) / 64, 256, 0, stream>>>(AXb, Xb, Wg, Rg, bias, out, N);
}

// Round 5
// 170.785 us; speedup vs baseline: 1.8859x; 1.3309x over previous
//
#include <hip/hip_runtime.h>

// SparseNodeConv: out = segment_sum((X@W)[edge_dst] by edge_src) + X@R + bias
// Strategy: AX = segment_sum(X[dst] by src)  (aggregate RAW features, linearity)
//           out = [AX | X](bf16) @ [W; R](bf16) + bias   via MFMA 16x16x32 bf16
//
// Edge grouping by src, coarse-first (NO per-node global atomics anywhere):
//  k_chist : per-block LDS coarse histogram (K=196 buckets of 256 nodes)
//            -> ~77K global atomics total (vs 1.6M per-node: 50MB atomic
//            write traffic was k_hist's 70us bottleneck).
//  k_cscan : 1-block scan of K coarse counts -> cbase/cursorC.
//  k_bucket: per-4096-edge-block LDS counting sort -> bucket-contiguous packs.
//  k_fine2 : one block per bucket: LDS per-node hist (LDS atomics) + scan,
//            writes per-node CSR offs NON-atomically (bucket owns its slice),
//            then scatters dst to exact CSR slot (writes in 32KB L2 window).
// N = 50000, E = 1600000, D = 128. Assumes N < 65536 (dst fits 16 bits).

typedef __attribute__((ext_vector_type(8))) short bf16x8;
typedef __attribute__((ext_vector_type(4))) float f32x4;

#define BSH 8  // coarse bucket = 256 nodes

__device__ __forceinline__ unsigned f2bf(float f) {
  unsigned u = __float_as_uint(f);
  return (u + 0x7fffu + ((u >> 16) & 1u)) >> 16;  // RNE
}
__device__ __forceinline__ unsigned pack2(float lo, float hi) {
  return f2bf(lo) | (f2bf(hi) << 16);
}
__device__ __forceinline__ float bflo(unsigned v) { return __uint_as_float(v << 16); }
__device__ __forceinline__ float bfhi(unsigned v) { return __uint_as_float(v & 0xffff0000u); }

// ---------- X (f32) -> Xb (bf16 packed u32 pairs) ----------
__global__ __launch_bounds__(256) void k_convert(const float4* __restrict__ X,
                                                 uint2* __restrict__ Xb, int n4) {
  int stride = gridDim.x * blockDim.x;
  for (int i = blockIdx.x * blockDim.x + threadIdx.x; i < n4; i += stride) {
    float4 v = X[i];
    uint2 o;
    o.x = pack2(v.x, v.y);
    o.y = pack2(v.z, v.w);
    Xb[i] = o;
  }
}

// ---------- coarse histogram (K counters) ----------
__global__ __launch_bounds__(256) void k_chist(const int* __restrict__ src,
                                               int* __restrict__ ccnt, int E_, int K_) {
  __shared__ int h[256];
  if (threadIdx.x < K_) h[threadIdx.x] = 0;
  __syncthreads();
  int base = blockIdx.x * 4096;
  int n = min(4096, E_ - base);
  for (int i = threadIdx.x; i < n; i += 256)
    atomicAdd(&h[((unsigned)src[base + i]) >> BSH], 1);
  __syncthreads();
  if (threadIdx.x < K_) {
    int c = h[threadIdx.x];
    if (c > 0) atomicAdd(&ccnt[threadIdx.x], c);
  }
}

// ---------- scan of K coarse counts ----------
__device__ __forceinline__ int incl_scan256(int v, int tid) {
  int lane = tid & 63, w = tid >> 6;
  int x = v;
#pragma unroll
  for (int d = 1; d < 64; d <<= 1) {
    int o = __shfl_up(x, d, 64);
    if (lane >= d) x += o;
  }
  __shared__ int wsum[4];
  if (lane == 63) wsum[w] = x;
  __syncthreads();
  if (w > 0) x += wsum[0];
  if (w > 1) x += wsum[1];
  if (w > 2) x += wsum[2];
  return x;
}

__global__ __launch_bounds__(256) void k_cscan(const int* __restrict__ ccnt,
                                               int* __restrict__ cbase,
                                               int* __restrict__ cursorC, int K_, int E_) {
  int t = threadIdx.x;
  int v = (t < K_) ? ccnt[t] : 0;
  int incl = incl_scan256(v, t);
  if (t < K_) {
    int e = incl - v;
    cbase[t] = e;
    cursorC[t] = e;
  }
  if (t == 0) cbase[K_] = E_;
}

// ---------- pass A: coarse scatter into 256-node buckets ----------
// pack = (src&255)<<16 | dst   (dst < 65536)
__global__ __launch_bounds__(256) void k_bucket(const int* __restrict__ src,
                                                const int* __restrict__ dst,
                                                int* __restrict__ cursorC,
                                                unsigned* __restrict__ packs,
                                                int E_, int K_) {
  __shared__ int lcnt[256];
  __shared__ int lbase[256];
  __shared__ unsigned lsrc[4096];
  __shared__ unsigned ldst[4096];
  int base = blockIdx.x * 4096;
  int n = min(4096, E_ - base);
  if (threadIdx.x < K_) lcnt[threadIdx.x] = 0;
  __syncthreads();
  for (int i = threadIdx.x; i < n; i += 256) {
    unsigned s = (unsigned)src[base + i];
    unsigned d = (unsigned)dst[base + i];
    lsrc[i] = s;
    ldst[i] = d;
    atomicAdd(&lcnt[s >> BSH], 1);
  }
  __syncthreads();
  if (threadIdx.x < K_) {
    int c = lcnt[threadIdx.x];
    lbase[threadIdx.x] = (c > 0) ? atomicAdd(&cursorC[threadIdx.x], c) : 0;
    lcnt[threadIdx.x] = 0;  // reuse as local cursor
  }
  __syncthreads();
  for (int i = threadIdx.x; i < n; i += 256) {
    unsigned s = lsrc[i], d = ldst[i];
    int b = s >> BSH;
    int r = atomicAdd(&lcnt[b], 1);
    packs[lbase[b] + r] = ((s & 255u) << 16) | d;
  }
}

// ---------- pass B: per-node hist + scan + fine scatter + offs write ----------
__global__ __launch_bounds__(256) void k_fine2(const int* __restrict__ cbase,
                                               const unsigned* __restrict__ packs,
                                               unsigned* __restrict__ sdst,
                                               int* __restrict__ offs,
                                               int N_, int E_) {
  __shared__ int lcnt[256];
  __shared__ int lbase[256];
  int tid = threadIdx.x;
  int b = blockIdx.x;
  int nodeBase = b << BSH;
  int nNodes = min(256, N_ - nodeBase);
  int beg = cbase[b];
  int n = cbase[b + 1] - beg;  // bucket edge count
  lcnt[tid] = 0;
  __syncthreads();
  // per-node histogram of this bucket (LDS atomics)
  for (int i = tid; i < n; i += 256) atomicAdd(&lcnt[packs[beg + i] >> 16], 1);
  __syncthreads();
  // exclusive scan of 256 counts (all threads participate; has __syncthreads)
  int v = lcnt[tid];
  int incl = incl_scan256(v, tid);
  int excl = incl - v;
  lbase[tid] = excl;
  // per-node CSR offsets: this bucket exclusively owns its node slice
  if (tid < nNodes) offs[nodeBase + tid] = beg + excl;
  if (b == gridDim.x - 1 && tid == 0) offs[N_] = E_;
  __syncthreads();
  lcnt[tid] = 0;  // reuse as fine cursor
  __syncthreads();
  // scatter (packs re-read: bucket is ~32KB, L2-hit)
  for (int i = tid; i < n; i += 256) {
    unsigned p = packs[beg + i];
    int sl = p >> 16;
    unsigned d = p & 0xffffu;
    int r = atomicAdd(&lcnt[sl], 1);
    sdst[beg + lbase[sl] + r] = d;
  }
}

// ---------- aggregation: AXb[i] = sum over bucket i of Xb[dst] ----------
// one wave per node; lane owns one u32 (2 bf16 cols); fp32 accumulate
__global__ __launch_bounds__(256) void k_agg(const unsigned* __restrict__ Xb,
                                             const int* __restrict__ offs,
                                             const int* __restrict__ sdst,
                                             unsigned* __restrict__ AXb, int N_) {
  int wid = (blockIdx.x * 256 + threadIdx.x) >> 6;
  int lane = threadIdx.x & 63;
  if (wid >= N_) return;
  int j = offs[wid], end = offs[wid + 1];
  float a0 = 0.f, a1 = 0.f;
  for (; j + 4 <= end; j += 4) {
    int d0 = sdst[j], d1 = sdst[j + 1], d2 = sdst[j + 2], d3 = sdst[j + 3];
    unsigned v0 = Xb[(size_t)d0 * 64 + lane];
    unsigned v1 = Xb[(size_t)d1 * 64 + lane];
    unsigned v2 = Xb[(size_t)d2 * 64 + lane];
    unsigned v3 = Xb[(size_t)d3 * 64 + lane];
    a0 += bflo(v0); a1 += bfhi(v0);
    a0 += bflo(v1); a1 += bfhi(v1);
    a0 += bflo(v2); a1 += bfhi(v2);
    a0 += bflo(v3); a1 += bfhi(v3);
  }
  for (; j < end; ++j) {
    unsigned v = Xb[(size_t)sdst[j] * 64 + lane];
    a0 += bflo(v); a1 += bfhi(v);
  }
  AXb[(size_t)wid * 64 + lane] = pack2(a0, a1);
}

// ---------- GEMM: out[N,128] = AXb@W + Xb@R + bias (MFMA 16x16x32 bf16) ----------
__global__ __launch_bounds__(256) void k_gemm(const unsigned* __restrict__ AXb,
                                              const unsigned* __restrict__ Xb,
                                              const float* __restrict__ Wg,
                                              const float* __restrict__ Rg,
                                              const float* __restrict__ bias,
                                              float* __restrict__ out, int N_) {
  __shared__ __align__(16) unsigned short Bt[128][136];
  int tid = threadIdx.x;
  int wave = tid >> 6, lane = tid & 63;
  int r = lane & 15, g = lane >> 4;
  int rowBase = (blockIdx.x * 4 + wave) * 16;
  int arow = rowBase + r;
  if (arow >= N_) arow = 0;  // clamp; stores are guarded

  bf16x8 fa[4], fx[4];
  const bf16x8* pA = (const bf16x8*)(AXb + (size_t)arow * 64);
  const bf16x8* pX = (const bf16x8*)(Xb + (size_t)arow * 64);
#pragma unroll
  for (int kk = 0; kk < 4; ++kk) {
    fa[kk] = pA[kk * 4 + g];
    fx[kk] = pX[kk * 4 + g];
  }

  f32x4 acc[8];
#pragma unroll
  for (int n = 0; n < 8; ++n) acc[n] = (f32x4){0.f, 0.f, 0.f, 0.f};

  for (int e = tid; e < 128 * 32; e += 256) {
    int c4 = (e & 31) * 4;
    int k = e >> 5;
    float4 v = *(const float4*)&Wg[k * 128 + c4];
    Bt[c4 + 0][k] = (unsigned short)f2bf(v.x);
    Bt[c4 + 1][k] = (unsigned short)f2bf(v.y);
    Bt[c4 + 2][k] = (unsigned short)f2bf(v.z);
    Bt[c4 + 3][k] = (unsigned short)f2bf(v.w);
  }
  __syncthreads();
#pragma unroll
  for (int n = 0; n < 8; ++n) {
    int col = n * 16 + r;
#pragma unroll
    for (int kk = 0; kk < 4; ++kk) {
      bf16x8 fb = *(const bf16x8*)&Bt[col][kk * 32 + g * 8];
      acc[n] = __builtin_amdgcn_mfma_f32_16x16x32_bf16(fa[kk], fb, acc[n], 0, 0, 0);
    }
  }
  __syncthreads();

  for (int e = tid; e < 128 * 32; e += 256) {
    int c4 = (e & 31) * 4;
    int k = e >> 5;
    float4 v = *(const float4*)&Rg[k * 128 + c4];
    Bt[c4 + 0][k] = (unsigned short)f2bf(v.x);
    Bt[c4 + 1][k] = (unsigned short)f2bf(v.y);
    Bt[c4 + 2][k] = (unsigned short)f2bf(v.z);
    Bt[c4 + 3][k] = (unsigned short)f2bf(v.w);
  }
  __syncthreads();
#pragma unroll
  for (int n = 0; n < 8; ++n) {
    int col = n * 16 + r;
#pragma unroll
    for (int kk = 0; kk < 4; ++kk) {
      bf16x8 fb = *(const bf16x8*)&Bt[col][kk * 32 + g * 8];
      acc[n] = __builtin_amdgcn_mfma_f32_16x16x32_bf16(fx[kk], fb, acc[n], 0, 0, 0);
    }
  }

#pragma unroll
  for (int n = 0; n < 8; ++n) {
    int col = n * 16 + r;
    float bv = bias[col];
#pragma unroll
    for (int jj = 0; jj < 4; ++jj) {
      int row = rowBase + g * 4 + jj;
      if (row < N_) out[(size_t)row * 128 + col] = acc[n][jj] + bv;
    }
  }
}

extern "C" void kernel_launch(void* const* d_in, const int* in_sizes, int n_in,
                              void* d_out, int out_size, void* d_ws, size_t ws_size,
                              hipStream_t stream) {
  const float* X = (const float*)d_in[0];
  const int* esrc = (const int*)d_in[1];
  const int* edst = (const int*)d_in[2];
  const float* Wg = (const float*)d_in[3];
  const float* Rg = (const float*)d_in[4];
  const float* bias = (const float*)d_in[5];
  float* out = (float*)d_out;

  int ND = in_sizes[0];  // N*D
  int E = in_sizes[1];
  int N = ND / 128;
  int K = (N + 255) >> BSH;  // 196 coarse buckets

  // persistent workspace
  char* ws = (char*)d_ws;
  size_t off = 0;
  auto wsalloc = [&](size_t b) {
    char* p = ws + off;
    off = (off + b + 255) & ~(size_t)255;
    return p;
  };
  int* offs = (int*)wsalloc((size_t)(N + 1) * 4);
  unsigned* sdst = (unsigned*)wsalloc((size_t)E * 4);
  unsigned* Xb = (unsigned*)wsalloc((size_t)N * 64 * 4);
  unsigned* AXb = (unsigned*)wsalloc((size_t)N * 64 * 4);
  // transient aliases inside the AXb region (all dead before k_agg writes AXb):
  unsigned* packs = AXb;                       // E u32 (6.4MB <= 12.8MB)
  int* ccnt = (int*)(AXb + (size_t)E);         // K ints
  int* cbase = ccnt + 512;                     // K+1 ints
  int* cursorC = cbase + 512;                  // K ints

  int nchunk = (E + 4095) / 4096;
  hipMemsetAsync(ccnt, 0, (size_t)K * 4, stream);
  k_convert<<<2048, 256, 0, stream>>>((const float4*)X, (uint2*)Xb, ND / 4);
  k_chist<<<nchunk, 256, 0, stream>>>(esrc, ccnt, E, K);
  k_cscan<<<1, 256, 0, stream>>>(ccnt, cbase, cursorC, K, E);
  k_bucket<<<nchunk, 256, 0, stream>>>(esrc, edst, cursorC, packs, E, K);
  k_fine2<<<K, 256, 0, stream>>>(cbase, packs, sdst, offs, N, E);
  k_agg<<<(N + 3) / 4, 256, 0, stream>>>(Xb, offs, (const int*)sdst, AXb, N);
  k_gemm<<<(N + 63) / 64, 256, 0, stream>>>(AXb, Xb, Wg, Rg, bias, out, N);
}